// Round 7
// baseline (135.584 us; speedup 1.0000x reference)
//
#include <hip/hip_runtime.h>
#include <math.h>

// Problem: B=4,S=2048,D=2048,E=64,K=2 -> tokens 8192, K-dim 2048, experts 64
#define NTOK 8192
#define DDIM 2048
#define NEXP 64
#define MT   16            // tokens per block (MFMA M)
#define NW   16            // waves per block (k-slices)
#define ASTR 72            // staged-row stride in halves (64 data + 8 pad)
#define CSTR 68            // partial-buffer row stride (floats)

#define GATED_SZ (NTOK * NEXP)
#define IDX_OFF  GATED_SZ
#define VALS_OFF (GATED_SZ + NTOK * 2)

#define NKSTEP (DDIM / 32)            // 64 MFMA k-steps
#define NTILE  (NEXP / 16)            // 4 n-tiles
#define BFRAG_HALVES ((size_t)NKSTEP * NTILE * 64 * 8)   // 131072 halves

typedef _Float16 f16x8 __attribute__((ext_vector_type(8)));
typedef _Float16 f16x4 __attribute__((ext_vector_type(4)));
typedef float    f32x4 __attribute__((ext_vector_type(4)));

// ---------------------------------------------------------------------------
// Pack W [E=64][D=2048] into MFMA B-fragments (fp16 hi + 4096-scaled lo).
// Frag (ks, nt): lane holds B[k=ks*32+(lane>>4)*8+j][n=nt*16+(lane&15)].
// Layout: Bh[((ks*4+nt)*64+lane)*8 + j]. (Verified absmax-stable.)
// ---------------------------------------------------------------------------
__global__ void pack_b_kernel(const float* __restrict__ W,
                              _Float16* __restrict__ Bh,
                              _Float16* __restrict__ Bl)
{
    const int tid  = blockIdx.x * blockDim.x + threadIdx.x;  // 0..16383
    const int lane = tid & 63;
    const int fid  = tid >> 6;
    const int ks   = fid >> 2;
    const int nt   = fid & 3;
    const int e    = nt * 16 + (lane & 15);
    const int k    = ks * 32 + (lane >> 4) * 8;
    const float* src = W + (size_t)e * DDIM + k;

    f16x8 hi, lo;
#pragma unroll
    for (int j = 0; j < 8; ++j) {
        const float v = src[j];
        const _Float16 h = (_Float16)v;
        hi[j] = h;
        lo[j] = (_Float16)((v - (float)h) * 4096.f);
    }
    *(f16x8*)(Bh + (size_t)tid * 8) = hi;
    *(f16x8*)(Bl + (size_t)tid * 8) = lo;
}

#define BFRAG(base, ks, nt) \
    (*(const f16x8*)((base) + ((((size_t)(ks)) * 4 + (nt)) * 64 + lane) * 8))

// fp32x4 -> fp16 hi + 4096-scaled lo residual (same split as pack_b).
static __device__ __forceinline__ void cvt_hilo4(float4 v, f16x4& h4, f16x4& l4)
{
    const float vv[4] = {v.x, v.y, v.z, v.w};
#pragma unroll
    for (int j = 0; j < 4; ++j) {
        const _Float16 hh = (_Float16)vv[j];
        h4[j] = hh;
        l4[j] = (_Float16)((vv[j] - (float)hh) * 4096.f);
    }
}

// ---------------------------------------------------------------------------
// Fused gate kernel. ROUND-7: 512 blocks x 1024 thr (16 waves) = 2 blocks/CU
// = 32 waves/CU (chip max). Empirical law from rounds 3-6: gate time tracks
// waves/CU only (8 waves: 71 us; 16 waves: ~30 us across three different
// structures) -- latency-bound, hidden by concurrent wave-streams. This
// doubles concurrency to the untested 32. VGPR must stay <= 64 for 8
// waves/SIMD: trimmed to single-buffer depth-2 prefetch (16 prefetch regs;
// round-3's 32-reg variant measured exactly 64 VGPR). Wave w owns k-slice
// [w*128, w*128+128) of 16 tokens x 64 experts; barrier-free main loop,
// per-wave private LDS staging (in-order per-wave ds ops; absmax=0.0 for 5
// rounds). logits = acc_hh + 2^-12 * acc_lo (x_lo, w_lo pre-scaled 4096).
// Epilogue: 16 k-slice partials summed ascending (verified in round 4),
// noise, top-2, softmax. LDS 72 KB/block (x2 = 144 <= 160 per CU).
// ---------------------------------------------------------------------------
__global__ __launch_bounds__(1024, 8) void gate_kernel(
    const float* __restrict__ x,
    const _Float16* __restrict__ Bh,
    const _Float16* __restrict__ Bl,
    const float* __restrict__ noise_w,
    const float* __restrict__ noise,
    float* __restrict__ out)
{
    // per-wave staging: [hi|lo] x 16 rows x ASTR halves = 4608 B; x16 waves
    // = 73728 B. cbuf (16*16*CSTR*4 = 69632 B) aliases after the barrier.
    __shared__ __align__(16) char smem_raw[NW * 2 * MT * ASTR * 2];

    const int tid  = threadIdx.x;
    const int lane = tid & 63;
    const int w    = __builtin_amdgcn_readfirstlane(tid >> 6);  // k-slice 0..15
    const int tokBase = blockIdx.x * MT;

    const int q = lane >> 4;               // 0..3
    const int m = lane & 15;               // 0..15

    _Float16* xs = (_Float16*)smem_raw + (size_t)w * (2 * MT * ASTR);

    // wave's x window: 16 tokens x 128 k starting at w*128
    const float* xw = x + (size_t)tokBase * DDIM + (size_t)w * 128;

    // hoisted epilogue operands (retire long before use)
    const float nwv = noise_w[lane];
    const float nz  = noise[(size_t)(tokBase + w) * NEXP + lane];

    f32x4 acc_hh[4], acc_lo[4];
#pragma unroll
    for (int nt = 0; nt < 4; ++nt) {
        acc_hh[nt] = (f32x4){0.f, 0.f, 0.f, 0.f};
        acc_lo[nt] = (f32x4){0.f, 0.f, 0.f, 0.f};
    }

    // Sub-chunk = 64 k (2 of them). Piece p: lane covers row p*4+q,
    // floats m*4..m*4+3 (16 lanes span a contiguous 256B row segment).
#define LOADSUB(s)                                                           \
    _Pragma("unroll")                                                        \
    for (int p = 0; p < 4; ++p) {                                            \
        rA[p] = *(const float4*)(xw + (size_t)(p * 4 + q) * DDIM             \
                                  + (s) * 64 + m * 4);                       \
    }

#define STAGESUB()                                                           \
    _Pragma("unroll")                                                        \
    for (int p = 0; p < 4; ++p) {                                            \
        f16x4 h4, l4;                                                        \
        cvt_hilo4(rA[p], h4, l4);                                            \
        const int off = (p * 4 + q) * ASTR + m * 4;                          \
        *(f16x4*)&xs[off] = h4;                                              \
        *(f16x4*)&xs[MT * ASTR + off] = l4;                                  \
    }

    // k-step stp within sub-chunk s: global ks = w*4 + s*2 + stp
#define COMPUTESUB(s)                                                        \
    _Pragma("unroll")                                                        \
    for (int stp = 0; stp < 2; ++stp) {                                      \
        const int ks = w * 4 + (s) * 2 + stp;                                \
        const f16x8 ah = *(const f16x8*)&xs[m * ASTR + stp * 32 + q * 8];    \
        const f16x8 al = *(const f16x8*)&xs[MT * ASTR + m * ASTR + stp * 32 + q * 8]; \
        _Pragma("unroll")                                                    \
        for (int nt = 0; nt < 4; ++nt) {                                     \
            const f16x8 bh = BFRAG(Bh, ks, nt);                              \
            const f16x8 bl = BFRAG(Bl, ks, nt);                              \
            acc_hh[nt] = __builtin_amdgcn_mfma_f32_16x16x32_f16(ah, bh, acc_hh[nt], 0, 0, 0); \
            acc_lo[nt] = __builtin_amdgcn_mfma_f32_16x16x32_f16(ah, bl, acc_lo[nt], 0, 0, 0); \
            acc_lo[nt] = __builtin_amdgcn_mfma_f32_16x16x32_f16(al, bh, acc_lo[nt], 0, 0, 0); \
        }                                                                    \
    }

    float4 rA[4];
    LOADSUB(0)          // load + stage sub-chunk 0
    STAGESUB()
    LOADSUB(1)          // sub-chunk 1 in flight across compute(0)
    COMPUTESUB(0)       // per-wave in-order LDS: sc0 reads before sc1 writes
    STAGESUB()
    COMPUTESUB(1)

#undef LOADSUB
#undef STAGESUB
#undef COMPUTESUB

    // ---- epilogue: 16 k-slice partials -> cbuf (aliases staging LDS) ----
    __syncthreads();    // all waves done reading their staging regions
    float* cbuf = (float*)smem_raw;   // [16 partials][16 tokens][CSTR]

    // C/D layout: col(e)=lane&15, row(t)=q*4+r
#pragma unroll
    for (int nt = 0; nt < 4; ++nt) {
        const int e = nt * 16 + m;
#pragma unroll
        for (int r = 0; r < 4; ++r) {
            const int t = q * 4 + r;
            cbuf[((w * MT) + t) * CSTR + e] =
                acc_hh[nt][r] + acc_lo[nt][r] * (1.f / 4096.f);
        }
    }
    __syncthreads();

    // Epilogue: wave w owns token w; lane = expert.
    {
        const int t   = w;
        const int tok = tokBase + t;
        const int e   = lane;

        float v = 0.f;
#pragma unroll
        for (int p = 0; p < 16; ++p)
            v += cbuf[((p * MT) + t) * CSTR + e];
        v += nz * nwv;

        // top-1: butterfly max, lax.top_k tie-break (lower index wins)
        float m1 = v; int i1 = e;
#pragma unroll
        for (int sh = 32; sh > 0; sh >>= 1) {
            float ov = __shfl_xor(m1, sh, 64);
            int   oi = __shfl_xor(i1, sh, 64);
            if (ov > m1 || (ov == m1 && oi < i1)) { m1 = ov; i1 = oi; }
        }
        float vm = (e == i1) ? -INFINITY : v;
        float m2 = vm; int i2 = e;
#pragma unroll
        for (int sh = 32; sh > 0; sh >>= 1) {
            float ov = __shfl_xor(m2, sh, 64);
            int   oi = __shfl_xor(i2, sh, 64);
            if (ov > m2 || (ov == m2 && oi < i2)) { m2 = ov; i2 = oi; }
        }

        const float e2  = expf(m2 - m1);
        const float inv = 1.f / (1.f + e2);
        const float p1  = inv;
        const float p2  = e2 * inv;

        float gval = 0.f;
        if (e == i1) gval = p1;
        else if (e == i2) gval = p2;
        out[(size_t)tok * NEXP + e] = gval;

        if (lane == 0) {
            out[IDX_OFF  + tok * 2 + 0] = (float)i1;
            out[IDX_OFF  + tok * 2 + 1] = (float)i2;
            out[VALS_OFF + tok * 2 + 0] = m1;
            out[VALS_OFF + tok * 2 + 1] = m2;
        }
    }
}

extern "C" void kernel_launch(void* const* d_in, const int* in_sizes, int n_in,
                              void* d_out, int out_size, void* d_ws, size_t ws_size,
                              hipStream_t stream) {
    const float* x     = (const float*)d_in[0];
    const float* W     = (const float*)d_in[1];
    const float* nw    = (const float*)d_in[2];
    const float* noise = (const float*)d_in[3];
    // d_in[4] is k==2, hardcoded
    float* out = (float*)d_out;

    _Float16* Bh = (_Float16*)d_ws;                 // 256 KB
    _Float16* Bl = Bh + BFRAG_HALVES;               // 256 KB

    hipLaunchKernelGGL(pack_b_kernel, dim3(64), dim3(256), 0, stream, W, Bh, Bl);

    hipLaunchKernelGGL(gate_kernel, dim3(NTOK / MT), dim3(1024), 0, stream,
                       x, Bh, Bl, nw, noise, out);
}

// Round 8
// 124.131 us; speedup vs baseline: 1.0923x; 1.0923x over previous
//
#include <hip/hip_runtime.h>
#include <math.h>

// Problem: B=4,S=2048,D=2048,E=64,K=2 -> tokens 8192, K-dim 2048, experts 64
#define NTOK 8192
#define DDIM 2048
#define NEXP 64
#define MT   16            // tokens per block (MFMA M)
#define NW   4             // waves per block (k-slices of 512)
#define ASTR 72            // staged-row stride in halves (64 data + 8 pad)
#define XL   (MT * ASTR)   // lo-plane offset within a wave's staging (halves)
#define CSTR 68            // partial-buffer row stride (floats)

#define GATED_SZ (NTOK * NEXP)
#define IDX_OFF  GATED_SZ
#define VALS_OFF (GATED_SZ + NTOK * 2)

#define NKSTEP (DDIM / 32)            // 64 MFMA k-steps
#define NTILE  (NEXP / 16)            // 4 n-tiles
#define BFRAG_HALVES ((size_t)NKSTEP * NTILE * 64 * 8)   // 131072 halves

typedef _Float16 f16x8 __attribute__((ext_vector_type(8)));
typedef _Float16 f16x4 __attribute__((ext_vector_type(4)));
typedef float    f32x4 __attribute__((ext_vector_type(4)));

// ---------------------------------------------------------------------------
// Pack W [E=64][D=2048] into MFMA B-fragments (fp16 hi + 4096-scaled lo).
// Frag (ks, nt): lane holds B[k=ks*32+(lane>>4)*8+j][n=nt*16+(lane&15)].
// Layout: Bh[((ks*4+nt)*64+lane)*8 + j]. (Verified absmax-stable.)
// ---------------------------------------------------------------------------
__global__ void pack_b_kernel(const float* __restrict__ W,
                              _Float16* __restrict__ Bh,
                              _Float16* __restrict__ Bl)
{
    const int tid  = blockIdx.x * blockDim.x + threadIdx.x;  // 0..16383
    const int lane = tid & 63;
    const int fid  = tid >> 6;
    const int ks   = fid >> 2;
    const int nt   = fid & 3;
    const int e    = nt * 16 + (lane & 15);
    const int k    = ks * 32 + (lane >> 4) * 8;
    const float* src = W + (size_t)e * DDIM + k;

    f16x8 hi, lo;
#pragma unroll
    for (int j = 0; j < 8; ++j) {
        const float v = src[j];
        const _Float16 h = (_Float16)v;
        hi[j] = h;
        lo[j] = (_Float16)((v - (float)h) * 4096.f);
    }
    *(f16x8*)(Bh + (size_t)tid * 8) = hi;
    *(f16x8*)(Bl + (size_t)tid * 8) = lo;
}

#define BFRAG(base, ks, nt) \
    (*(const f16x8*)((base) + ((((size_t)(ks)) * 4 + (nt)) * 64 + lane) * 8))

// fp32x4 -> fp16 hi + 4096-scaled lo residual (same split as pack_b).
static __device__ __forceinline__ void cvt_hilo4(float4 v, f16x4& h4, f16x4& l4)
{
    const float vv[4] = {v.x, v.y, v.z, v.w};
#pragma unroll
    for (int j = 0; j < 4; ++j) {
        const _Float16 hh = (_Float16)vv[j];
        h4[j] = hh;
        l4[j] = (_Float16)((vv[j] - (float)hh) * 4096.f);
    }
}

// ---------------------------------------------------------------------------
// Fused gate kernel. ROUND-8: 2048 blocks x 256 thr (4 waves) -> 8 blocks/CU
// by LDS (18.4 KB), target 24-32 waves/CU WITH a deep per-wave pipeline.
// r7 post-mortem: 32 waves/CU regressed because (a) per-wave k=128 left no
// steady-state to hide latency in, (b) grid=512 at 2 resident blocks/CU ran
// in lockstep (no stagger). This config fixes both: wave w owns k-slice
// [w*512, +512) = 8 sub-chunks of 64 k (deep rotation pipeline: load s+1
// issued before compute s), and 2048 small blocks refill continuously so
// barriers/epilogues stagger across blocks. Main loop stays BARRIER-FREE
// with per-wave private LDS staging (in-order per-wave ds ops; absmax=0.0
// for 7 rounds). logits = acc_hh + 2^-12 * acc_lo (x_lo, w_lo pre-scaled
// by 4096). Epilogue: 4 k-slice partials summed ascending, noise, top-2,
// softmax (logic unchanged). launch_bounds(256,6): combined reg cap ~85.
// ---------------------------------------------------------------------------
__global__ __launch_bounds__(256, 6) void gate_kernel(
    const float* __restrict__ x,
    const _Float16* __restrict__ Bh,
    const _Float16* __restrict__ Bl,
    const float* __restrict__ noise_w,
    const float* __restrict__ noise,
    float* __restrict__ out)
{
    // per-wave staging: [hi|lo] x 16 rows x ASTR halves = 4608 B; x4 waves
    // = 18432 B. cbuf (4*16*CSTR*4 = 17408 B) aliases after the barrier.
    __shared__ __align__(16) char smem_raw[NW * 2 * MT * ASTR * 2];

    const int tid  = threadIdx.x;
    const int lane = tid & 63;
    const int w    = __builtin_amdgcn_readfirstlane(tid >> 6);  // k-slice 0..3
    const int tokBase = blockIdx.x * MT;

    const int q = lane >> 4;               // 0..3
    const int m = lane & 15;               // 0..15

    _Float16* xs = (_Float16*)smem_raw + (size_t)w * (2 * MT * ASTR);

    // wave's x window: 16 tokens x 512 k starting at w*512
    const float* xw = x + (size_t)tokBase * DDIM + (size_t)w * 512;

    // hoisted epilogue operands (retire long before use)
    const float nwv = noise_w[lane];
    float nz[4];
#pragma unroll
    for (int i = 0; i < 4; ++i)
        nz[i] = noise[(size_t)(tokBase + w * 4 + i) * NEXP + lane];

    f32x4 acc_hh[4], acc_lo[4];
#pragma unroll
    for (int nt = 0; nt < 4; ++nt) {
        acc_hh[nt] = (f32x4){0.f, 0.f, 0.f, 0.f};
        acc_lo[nt] = (f32x4){0.f, 0.f, 0.f, 0.f};
    }

    // Sub-chunk = 64 k (8 of them). Piece p: lane covers row p*4+q,
    // floats m*4..m*4+3 (16 lanes span a contiguous 256B row segment).
#define LOADSUB(s)                                                           \
    _Pragma("unroll")                                                        \
    for (int p = 0; p < 4; ++p) {                                            \
        rA[p] = *(const float4*)(xw + (size_t)(p * 4 + q) * DDIM             \
                                  + (s) * 64 + m * 4);                       \
    }

#define STAGESUB()                                                           \
    _Pragma("unroll")                                                        \
    for (int p = 0; p < 4; ++p) {                                            \
        f16x4 h4, l4;                                                        \
        cvt_hilo4(rA[p], h4, l4);                                            \
        const int off = (p * 4 + q) * ASTR + m * 4;                          \
        *(f16x4*)&xs[off] = h4;                                              \
        *(f16x4*)&xs[XL + off] = l4;                                         \
    }

    // k-step stp within sub-chunk s: global ks = w*16 + s*2 + stp
#define COMPUTESUB(s)                                                        \
    _Pragma("unroll")                                                        \
    for (int stp = 0; stp < 2; ++stp) {                                      \
        const int ks = w * 16 + (s) * 2 + stp;                               \
        const f16x8 ah = *(const f16x8*)&xs[m * ASTR + stp * 32 + q * 8];    \
        const f16x8 al = *(const f16x8*)&xs[XL + m * ASTR + stp * 32 + q * 8]; \
        _Pragma("unroll")                                                    \
        for (int nt = 0; nt < 4; ++nt) {                                     \
            const f16x8 bh = BFRAG(Bh, ks, nt);                              \
            const f16x8 bl = BFRAG(Bl, ks, nt);                              \
            acc_hh[nt] = __builtin_amdgcn_mfma_f32_16x16x32_f16(ah, bh, acc_hh[nt], 0, 0, 0); \
            acc_lo[nt] = __builtin_amdgcn_mfma_f32_16x16x32_f16(ah, bl, acc_lo[nt], 0, 0, 0); \
            acc_lo[nt] = __builtin_amdgcn_mfma_f32_16x16x32_f16(al, bh, acc_lo[nt], 0, 0, 0); \
        }                                                                    \
    }

    float4 rA[4];
    LOADSUB(0)          // cold start
    STAGESUB()
#pragma unroll
    for (int s = 0; s < 7; ++s) {
        LOADSUB(s + 1)  // next sub-chunk in flight across compute(s)
        COMPUTESUB(s)   // per-wave in-order LDS: reads s before writes s+1
        STAGESUB()      // waits the load issued one compute phase earlier
    }
    COMPUTESUB(7)

#undef LOADSUB
#undef STAGESUB
#undef COMPUTESUB

    // ---- epilogue: 4 k-slice partials -> cbuf (aliases staging LDS) ----
    __syncthreads();    // all waves done reading their staging regions
    float* cbuf = (float*)smem_raw;   // [4 partials][16 tokens][CSTR]

    // C/D layout: col(e)=lane&15, row(t)=q*4+r
#pragma unroll
    for (int nt = 0; nt < 4; ++nt) {
        const int e = nt * 16 + m;
#pragma unroll
        for (int r = 0; r < 4; ++r) {
            const int t = q * 4 + r;
            cbuf[((w * MT) + t) * CSTR + e] =
                acc_hh[nt][r] + acc_lo[nt][r] * (1.f / 4096.f);
        }
    }
    __syncthreads();

    // Epilogue: wave w owns tokens w*4 .. w*4+3; lane = expert.
#pragma unroll
    for (int i = 0; i < 4; ++i) {
        const int t   = w * 4 + i;
        const int tok = tokBase + t;
        const int e   = lane;

        float v = 0.f;
#pragma unroll
        for (int p = 0; p < 4; ++p)
            v += cbuf[((p * MT) + t) * CSTR + e];
        v += nz[i] * nwv;

        // top-1: butterfly max, lax.top_k tie-break (lower index wins)
        float m1 = v; int i1 = e;
#pragma unroll
        for (int sh = 32; sh > 0; sh >>= 1) {
            float ov = __shfl_xor(m1, sh, 64);
            int   oi = __shfl_xor(i1, sh, 64);
            if (ov > m1 || (ov == m1 && oi < i1)) { m1 = ov; i1 = oi; }
        }
        float vm = (e == i1) ? -INFINITY : v;
        float m2 = vm; int i2 = e;
#pragma unroll
        for (int sh = 32; sh > 0; sh >>= 1) {
            float ov = __shfl_xor(m2, sh, 64);
            int   oi = __shfl_xor(i2, sh, 64);
            if (ov > m2 || (ov == m2 && oi < i2)) { m2 = ov; i2 = oi; }
        }

        const float e2  = expf(m2 - m1);
        const float inv = 1.f / (1.f + e2);
        const float p1  = inv;
        const float p2  = e2 * inv;

        float gval = 0.f;
        if (e == i1) gval = p1;
        else if (e == i2) gval = p2;
        out[(size_t)tok * NEXP + e] = gval;

        if (lane == 0) {
            out[IDX_OFF  + tok * 2 + 0] = (float)i1;
            out[IDX_OFF  + tok * 2 + 1] = (float)i2;
            out[VALS_OFF + tok * 2 + 0] = m1;
            out[VALS_OFF + tok * 2 + 1] = m2;
        }
    }
}

extern "C" void kernel_launch(void* const* d_in, const int* in_sizes, int n_in,
                              void* d_out, int out_size, void* d_ws, size_t ws_size,
                              hipStream_t stream) {
    const float* x     = (const float*)d_in[0];
    const float* W     = (const float*)d_in[1];
    const float* nw    = (const float*)d_in[2];
    const float* noise = (const float*)d_in[3];
    // d_in[4] is k==2, hardcoded
    float* out = (float*)d_out;

    _Float16* Bh = (_Float16*)d_ws;                 // 256 KB
    _Float16* Bl = Bh + BFRAG_HALVES;               // 256 KB

    hipLaunchKernelGGL(pack_b_kernel, dim3(64), dim3(256), 0, stream, W, Bh, Bl);

    hipLaunchKernelGGL(gate_kernel, dim3(NTOK / MT), dim3(256), 0, stream,
                       x, Bh, Bl, nw, noise, out);
}

// Round 9
// 118.279 us; speedup vs baseline: 1.1463x; 1.0495x over previous
//
#include <hip/hip_runtime.h>
#include <math.h>

// Problem: B=4,S=2048,D=2048,E=64,K=2 -> tokens 8192, K-dim 2048, experts 64
#define NTOK 8192
#define DDIM 2048
#define NEXP 64
#define MT   16            // tokens per block (now the MFMA N dimension)
#define NW   8             // waves per block (k-slices of 256)
#define CSTR 68            // partial-buffer row stride (floats)

#define GATED_SZ (NTOK * NEXP)
#define IDX_OFF  GATED_SZ
#define VALS_OFF (GATED_SZ + NTOK * 2)

#define NKSTEP (DDIM / 32)            // 64 MFMA k-steps
#define NTILE  (NEXP / 16)            // 4 expert-tiles
#define BFRAG_HALVES ((size_t)NKSTEP * NTILE * 64 * 8)   // 131072 halves

typedef _Float16 f16x8 __attribute__((ext_vector_type(8)));
typedef float    f32x4 __attribute__((ext_vector_type(4)));

// ---------------------------------------------------------------------------
// Pack W [E=64][D=2048] into MFMA fragments (fp16 hi + 4096-scaled lo).
// Per-lane mapping: lane holds W[e = nt*16 + (lane&15)][k = ks*32 + (lane>>4)*8 + j]
// at Bh[((ks*4+nt)*64+lane)*8 + j]. UNCHANGED from all prior rounds; with the
// round-9 operand swap this byte-identical layout now serves as the MFMA
// A-operand (experts = M rows) instead of the B-operand. (A and B fragments
// of mfma_f32_16x16x32_f16 share the same per-lane register layout.)
// ---------------------------------------------------------------------------
__global__ void pack_b_kernel(const float* __restrict__ W,
                              _Float16* __restrict__ Bh,
                              _Float16* __restrict__ Bl)
{
    const int tid  = blockIdx.x * blockDim.x + threadIdx.x;  // 0..16383
    const int lane = tid & 63;
    const int fid  = tid >> 6;
    const int ks   = fid >> 2;
    const int nt   = fid & 3;
    const int e    = nt * 16 + (lane & 15);
    const int k    = ks * 32 + (lane >> 4) * 8;
    const float* src = W + (size_t)e * DDIM + k;

    f16x8 hi, lo;
#pragma unroll
    for (int j = 0; j < 8; ++j) {
        const float v = src[j];
        const _Float16 h = (_Float16)v;
        hi[j] = h;
        lo[j] = (_Float16)((v - (float)h) * 4096.f);
    }
    *(f16x8*)(Bh + (size_t)tid * 8) = hi;
    *(f16x8*)(Bl + (size_t)tid * 8) = lo;
}

#define BFRAG(base, ks, et) \
    (*(const f16x8*)((base) + ((((size_t)(ks)) * 4 + (et)) * 64 + lane) * 8))

// two float4 (8 consecutive fp32) -> fp16 hi + 4096-scaled lo residual
static __device__ __forceinline__ void cvt_hilo8(float4 v0, float4 v1,
                                                 f16x8& h8, f16x8& l8)
{
    const float vv[8] = {v0.x, v0.y, v0.z, v0.w, v1.x, v1.y, v1.z, v1.w};
#pragma unroll
    for (int j = 0; j < 8; ++j) {
        const _Float16 hh = (_Float16)vv[j];
        h8[j] = hh;
        l8[j] = (_Float16)((vv[j] - (float)hh) * 4096.f);
    }
}

// ---------------------------------------------------------------------------
// Fused gate kernel. ROUND-9: OPERAND SWAP -- experts as MFMA M, tokens as N.
// This deletes the x staging chain entirely: the x B-fragment is 32
// CONTIGUOUS bytes of one token row per lane (two float4 -> in-reg cvt),
// so the main loop has ZERO LDS traffic and zero main-loop barriers; W
// A-fragments come from the unchanged packed Bh/Bl (L2-resident). Every
// prior structure (rounds 0-8, all ~27-50us) kept the
// global->cvt->ds_write->ds_read->MFMA chain; all other knobs (barriers,
// prefetch depth, MT, occupancy 8/16/32 waves per CU) proved non-causal.
// 512 blocks x 512 thr (8 waves, 16 waves/CU -- the measured optimum).
// Wave w owns k-slice [w*256, +256) = 8 k-steps; depth-2 x prefetch.
// C/D (verified mapping): row=expert=et*16+q*4+r, col=token=m.
// logits = acc_hh + 2^-12 * acc_lo; 8 k-partials summed ascending; top-2
// epilogue textually unchanged from the verified r3/r6 kernel.
// ---------------------------------------------------------------------------
__global__ __launch_bounds__(512, 2) void gate_kernel(
    const float* __restrict__ x,
    const _Float16* __restrict__ Bh,
    const _Float16* __restrict__ Bl,
    const float* __restrict__ noise_w,
    const float* __restrict__ noise,
    float* __restrict__ out)
{
    __shared__ float cbuf[NW * MT * CSTR];   // 34816 B; the ONLY LDS

    const int tid  = threadIdx.x;
    const int lane = tid & 63;
    const int w    = __builtin_amdgcn_readfirstlane(tid >> 6);  // k-slice 0..7
    const int tokBase = blockIdx.x * MT;

    const int q = lane >> 4;               // 0..3 (k-quad)
    const int m = lane & 15;               // 0..15 (token within block)

    // lane's x source: token row m, k window [w*256 + q*8, ...)
    const float* xp = x + (size_t)(tokBase + m) * DDIM + w * 256 + q * 8;

    // hoisted epilogue operands
    const float nwv = noise_w[lane];
    const float nz0 = noise[(size_t)(tokBase + w * 2)     * NEXP + lane];
    const float nz1 = noise[(size_t)(tokBase + w * 2 + 1) * NEXP + lane];

    f32x4 acc_hh[4], acc_lo[4];            // [expert-tile]
#pragma unroll
    for (int et = 0; et < 4; ++et) {
        acc_hh[et] = (f32x4){0.f, 0.f, 0.f, 0.f};
        acc_lo[et] = (f32x4){0.f, 0.f, 0.f, 0.f};
    }

    // x load for k-step s: lane reads 8 consecutive floats (32 B) of its
    // token row. Per instruction: 16 rows x 4 q-lanes x 16 B; the float4
    // pair covers 128 B/row contiguous (L1 merges the split).
#define XLOAD(buf, s)                                                        \
    {                                                                        \
        buf[0] = *(const float4*)(xp + (s) * 32);                            \
        buf[1] = *(const float4*)(xp + (s) * 32 + 4);                        \
    }

    // one 32-k MFMA step: ks = w*8 + s. A = W frags (packed, L2),
    // B = x frag (in-reg). Same 3-MFMA hi/lo order as all verified rounds.
#define STEP(s, buf)                                                         \
    {                                                                        \
        f16x8 xh_, xl_;                                                      \
        cvt_hilo8(buf[0], buf[1], xh_, xl_);                                 \
        if ((s) + 2 < 8) XLOAD(buf, (s) + 2)   /* refill parity buffer */    \
        const int ks = w * 8 + (s);                                          \
        _Pragma("unroll")                                                    \
        for (int et = 0; et < 4; ++et) {                                     \
            const f16x8 wh_ = BFRAG(Bh, ks, et);                             \
            const f16x8 wl_ = BFRAG(Bl, ks, et);                             \
            acc_hh[et] = __builtin_amdgcn_mfma_f32_16x16x32_f16(wh_, xh_, acc_hh[et], 0, 0, 0); \
            acc_lo[et] = __builtin_amdgcn_mfma_f32_16x16x32_f16(wh_, xl_, acc_lo[et], 0, 0, 0); \
            acc_lo[et] = __builtin_amdgcn_mfma_f32_16x16x32_f16(wl_, xh_, acc_lo[et], 0, 0, 0); \
        }                                                                    \
    }

    float4 bufA[2], bufB[2];
    XLOAD(bufA, 0)      // depth-2 x prefetch: two k-steps always in flight
    XLOAD(bufB, 1)
    STEP(0, bufA)
    STEP(1, bufB)
    STEP(2, bufA)
    STEP(3, bufB)
    STEP(4, bufA)
    STEP(5, bufB)
    STEP(6, bufA)
    STEP(7, bufB)

#undef XLOAD
#undef STEP

    // ---- combine hi/lo, write wave's k-partial ----
    // C/D: row(expert) = et*16 + q*4 + r, col(token) = m. acc[et][r] are 4
    // consecutive experts -> one float4 store per et. No pre-barrier needed:
    // each wave writes only its own cbuf[w] slice (no aliasing this round).
#pragma unroll
    for (int et = 0; et < 4; ++et) {
        f32x4 cv;
#pragma unroll
        for (int r = 0; r < 4; ++r)
            cv[r] = acc_hh[et][r] + acc_lo[et][r] * (1.f / 4096.f);
        *(f32x4*)&cbuf[((size_t)w * MT + m) * CSTR + et * 16 + q * 4] = cv;
    }
    __syncthreads();

    // Epilogue: wave w owns tokens w*2, w*2+1; lane = expert.
#pragma unroll
    for (int i = 0; i < 2; ++i) {
        const int t   = w * 2 + i;
        const int tok = tokBase + t;
        const int e   = lane;

        float v = 0.f;
#pragma unroll
        for (int p = 0; p < 8; ++p)
            v += cbuf[((size_t)p * MT + t) * CSTR + e];
        v += (i ? nz1 : nz0) * nwv;

        // top-1: butterfly max, lax.top_k tie-break (lower index wins)
        float m1 = v; int i1 = e;
#pragma unroll
        for (int sh = 32; sh > 0; sh >>= 1) {
            float ov = __shfl_xor(m1, sh, 64);
            int   oi = __shfl_xor(i1, sh, 64);
            if (ov > m1 || (ov == m1 && oi < i1)) { m1 = ov; i1 = oi; }
        }
        float vm = (e == i1) ? -INFINITY : v;
        float m2 = vm; int i2 = e;
#pragma unroll
        for (int sh = 32; sh > 0; sh >>= 1) {
            float ov = __shfl_xor(m2, sh, 64);
            int   oi = __shfl_xor(i2, sh, 64);
            if (ov > m2 || (ov == m2 && oi < i2)) { m2 = ov; i2 = oi; }
        }

        const float e2  = expf(m2 - m1);
        const float inv = 1.f / (1.f + e2);
        const float p1  = inv;
        const float p2  = e2 * inv;

        float gval = 0.f;
        if (e == i1) gval = p1;
        else if (e == i2) gval = p2;
        out[(size_t)tok * NEXP + e] = gval;

        if (lane == 0) {
            out[IDX_OFF  + tok * 2 + 0] = (float)i1;
            out[IDX_OFF  + tok * 2 + 1] = (float)i2;
            out[VALS_OFF + tok * 2 + 0] = m1;
            out[VALS_OFF + tok * 2 + 1] = m2;
        }
    }
}

extern "C" void kernel_launch(void* const* d_in, const int* in_sizes, int n_in,
                              void* d_out, int out_size, void* d_ws, size_t ws_size,
                              hipStream_t stream) {
    const float* x     = (const float*)d_in[0];
    const float* W     = (const float*)d_in[1];
    const float* nw    = (const float*)d_in[2];
    const float* noise = (const float*)d_in[3];
    // d_in[4] is k==2, hardcoded
    float* out = (float*)d_out;

    _Float16* Bh = (_Float16*)d_ws;                 // 256 KB
    _Float16* Bl = Bh + BFRAG_HALVES;               // 256 KB

    hipLaunchKernelGGL(pack_b_kernel, dim3(64), dim3(256), 0, stream, W, Bh, Bl);

    hipLaunchKernelGGL(gate_kernel, dim3(NTOK / MT), dim3(512), 0, stream,
                       x, Bh, Bl, nw, noise, out);
}